// Round 5
// baseline (339.437 us; speedup 1.0000x reference)
//
#include <hip/hip_runtime.h>
#include <math.h>

// ---------------------------------------------------------------------------
// TGN TransformerConv forward — 6 dispatches:
//   memset(counts|cursor)
//   K1 prep_hist: Wt bf16[448][128] (fused W^T) + ball f32[448] + dst histogram
//   K2 scan:      single-block (1024t) exclusive scan counts -> offs (CSR)
//   K3 scatter:   sorted_src by dst
//   K4 qkv_mfma:  gather(emb,mem)[n_id] fused into A-staging; bf16 MFMA GEMM
//                 [N,128]@[128,448] -> q,k,v bf16 + skip f32 (d_out).
//                 A-tile staged once, A-frags cached in regs across 7 col-tiles.
//   K5 attn:      4 nodes/wave, 8 lanes/head (8 dims each, uint4 loads),
//                 no-max softmax (|score|<~6), 2-deep prefetch, per-lane
//                 degree predication.
// R4: attn latency/VALU-bound (50% VALU, 37% hbm), rest-of-pipeline ~215us.
// ---------------------------------------------------------------------------

typedef unsigned int uint32;
typedef unsigned short ushort16;
typedef __attribute__((ext_vector_type(8))) short short8;
typedef __attribute__((ext_vector_type(4))) float floatx4;

__device__ __forceinline__ ushort16 f2bf(float f) {
  union { float f; uint32 u; } x; x.f = f;
  uint32 r = x.u + 0x7fffu + ((x.u >> 16) & 1u);   // RNE
  return (ushort16)(r >> 16);
}
__device__ __forceinline__ float bf_lo(uint32 u) {
  union { uint32 u; float f; } x; x.u = u << 16; return x.f;
}
__device__ __forceinline__ float bf_hi(uint32 u) {
  union { uint32 u; float f; } x; x.u = u & 0xffff0000u; return x.f;
}
__device__ __forceinline__ void unpack8(uint4 u, float* f) {
  f[0] = bf_lo(u.x); f[1] = bf_hi(u.x); f[2] = bf_lo(u.y); f[3] = bf_hi(u.y);
  f[4] = bf_lo(u.z); f[5] = bf_hi(u.z); f[6] = bf_lo(u.w); f[7] = bf_hi(u.w);
}
__device__ __forceinline__ uint4 pack8(float4 a, float4 b) {
  uint4 r;
  r.x = (uint32)f2bf(a.x) | ((uint32)f2bf(a.y) << 16);
  r.y = (uint32)f2bf(a.z) | ((uint32)f2bf(a.w) << 16);
  r.z = (uint32)f2bf(b.x) | ((uint32)f2bf(b.y) << 16);
  r.w = (uint32)f2bf(b.z) | ((uint32)f2bf(b.w) << 16);
  return r;
}

// ---- K1: fuse+transpose weights to bf16 [448][128] + biases + histogram ----
__global__ __launch_bounds__(256) void prep_hist_kernel(
    const float* __restrict__ Wq, const float* __restrict__ bq,
    const float* __restrict__ Wk, const float* __restrict__ bk,
    const float* __restrict__ Wv, const float* __restrict__ bv,
    const float* __restrict__ Ws, const float* __restrict__ bs,
    ushort16* __restrict__ Wt, float* __restrict__ ball,
    const int* __restrict__ dstA, int E, int* __restrict__ counts) {
  int idx = blockIdx.x * 256 + threadIdx.x;
  if (idx < 448 * 128) {
    int n = idx >> 7, k = idx & 127;
    float w;
    if (n < 128)      w = Wq[k * 128 + n];
    else if (n < 256) w = Wk[k * 128 + (n - 128)];
    else if (n < 384) w = Wv[k * 128 + (n - 256)];
    else              w = Ws[k * 64 + (n - 384)];
    Wt[idx] = f2bf(w);
  }
  if (idx < 448) {
    float b;
    if (idx < 128)      b = bq[idx];
    else if (idx < 256) b = bk[idx - 128];
    else if (idx < 384) b = bv[idx - 256];
    else                b = bs[idx - 384];
    ball[idx] = b;
  }
  if (idx < E) atomicAdd(&counts[dstA[idx]], 1);
}

// ---- K2: single-block exclusive scan (1024 threads, wave-shuffle) ----------
__global__ __launch_bounds__(1024) void scan_kernel(
    const int* __restrict__ counts, int* __restrict__ offs, int N, int E) {
  __shared__ int ws[16];
  int t = threadIdx.x;
  int lane = t & 63, wave = t >> 6;
  int running = 0;
  int nIter = (N + 1023) >> 10;
  for (int it = 0; it < nIter; ++it) {
    int idx = (it << 10) + t;
    int v = (idx < N) ? counts[idx] : 0;
    int p = v;   // inclusive wave scan
#pragma unroll
    for (int o = 1; o < 64; o <<= 1) {
      int u = __shfl_up(p, o);
      if (lane >= o) p += u;
    }
    if (lane == 63) ws[wave] = p;
    __syncthreads();
    int wpre = 0, tot = 0;
#pragma unroll
    for (int w = 0; w < 16; ++w) {
      int s = ws[w];
      if (w < wave) wpre += s;
      tot += s;
    }
    if (idx < N) offs[idx] = running + wpre + (p - v);  // exclusive
    running += tot;
    __syncthreads();
  }
  if (t == 0) offs[N] = E;
}

// ---- K3: scatter to CSR ----------------------------------------------------
__global__ __launch_bounds__(256) void scatter_kernel(
    const int* __restrict__ srcA, const int* __restrict__ dstA, int E,
    const int* __restrict__ offs, int* __restrict__ cursor,
    int* __restrict__ sorted_src) {
  int e = blockIdx.x * blockDim.x + threadIdx.x;
  if (e < E) {
    int d = dstA[e];
    int p = offs[d] + atomicAdd(&cursor[d], 1);
    sorted_src[p] = srcA[e];
  }
}

// ---- K4: gather-fused bf16 MFMA GEMM: concat(emb,mem)[n_id] @ [128,448] ----
#define LDA 136  // 128 + 8 pad (bf16): ds_read_b128 frags land 2-way = free
__global__ __launch_bounds__(256) void qkv_mfma_kernel(
    const int* __restrict__ n_id, const float* __restrict__ embtab,
    const float* __restrict__ memtab,
    const ushort16* __restrict__ Wt, const float* __restrict__ ball,
    ushort16* __restrict__ qb, ushort16* __restrict__ kb, ushort16* __restrict__ vb,
    float* __restrict__ outskip, int N) {
  __shared__ ushort16 As[128 * LDA];
  __shared__ ushort16 Bs[64 * LDA];
  int t = threadIdx.x;
  int row0 = blockIdx.x * 128;

  // stage A with gather+convert: 128 rows x 16 chunks of 8 f32 -> 8 bf16 (16B)
#pragma unroll
  for (int rep = 0; rep < 8; ++rep) {
    int idx = rep * 256 + t;
    int r = idx >> 4, c = idx & 15;
    int grow = row0 + r;
    uint4 outv = make_uint4(0u, 0u, 0u, 0u);
    if (grow < N) {
      int srcrow = n_id[grow];
      const float* srcp = (c < 8) ? (embtab + (size_t)srcrow * 64 + c * 8)
                                  : (memtab + (size_t)srcrow * 64 + (c - 8) * 8);
      float4 f0 = *(const float4*)srcp;
      float4 f1 = *(const float4*)(srcp + 4);
      outv = pack8(f0, f1);
    }
    *(uint4*)&As[r * LDA + c * 8] = outv;
  }
  __syncthreads();

  int wave = t >> 6, lane = t & 63;
  int m_base = wave * 32;
  int lrow = lane & 15, quad = lane >> 4;

  // cache A fragments in registers (reused across all 7 col-tiles)
  short8 af0[4], af1[4];
#pragma unroll
  for (int kk = 0; kk < 4; ++kk) {
    int koff = kk * 32 + quad * 8;
    af0[kk] = *(const short8*)&As[(m_base + lrow) * LDA + koff];
    af1[kk] = *(const short8*)&As[(m_base + 16 + lrow) * LDA + koff];
  }

  for (int ct = 0; ct < 7; ++ct) {
    int col0 = ct * 64;
    // stage B tile 64x128
#pragma unroll
    for (int rep = 0; rep < 4; ++rep) {
      int idx = rep * 256 + t;
      int r = idx >> 4, c = idx & 15;
      uint4 val = *(const uint4*)(Wt + (size_t)(col0 + r) * 128 + c * 8);
      *(uint4*)&Bs[r * LDA + c * 8] = val;
    }
    __syncthreads();

    floatx4 acc[2][4];
#pragma unroll
    for (int i = 0; i < 2; ++i)
#pragma unroll
      for (int j = 0; j < 4; ++j) acc[i][j] = (floatx4)(0.f);

#pragma unroll
    for (int kk = 0; kk < 4; ++kk) {
      int koff = kk * 32 + quad * 8;
      short8 b0 = *(const short8*)&Bs[(lrow) * LDA + koff];
      short8 b1 = *(const short8*)&Bs[(16 + lrow) * LDA + koff];
      short8 b2 = *(const short8*)&Bs[(32 + lrow) * LDA + koff];
      short8 b3 = *(const short8*)&Bs[(48 + lrow) * LDA + koff];
      acc[0][0] = __builtin_amdgcn_mfma_f32_16x16x32_bf16(af0[kk], b0, acc[0][0], 0, 0, 0);
      acc[0][1] = __builtin_amdgcn_mfma_f32_16x16x32_bf16(af0[kk], b1, acc[0][1], 0, 0, 0);
      acc[0][2] = __builtin_amdgcn_mfma_f32_16x16x32_bf16(af0[kk], b2, acc[0][2], 0, 0, 0);
      acc[0][3] = __builtin_amdgcn_mfma_f32_16x16x32_bf16(af0[kk], b3, acc[0][3], 0, 0, 0);
      acc[1][0] = __builtin_amdgcn_mfma_f32_16x16x32_bf16(af1[kk], b0, acc[1][0], 0, 0, 0);
      acc[1][1] = __builtin_amdgcn_mfma_f32_16x16x32_bf16(af1[kk], b1, acc[1][1], 0, 0, 0);
      acc[1][2] = __builtin_amdgcn_mfma_f32_16x16x32_bf16(af1[kk], b2, acc[1][2], 0, 0, 0);
      acc[1][3] = __builtin_amdgcn_mfma_f32_16x16x32_bf16(af1[kk], b3, acc[1][3], 0, 0, 0);
    }

    // epilogue: C/D layout col=lane&15, row=quad*4+reg. ct: 0,1=q 2,3=k 4,5=v 6=skip
#pragma unroll
    for (int jt = 0; jt < 4; ++jt) {
      int gcol = col0 + jt * 16 + lrow;
      float bias = ball[gcol];
#pragma unroll
      for (int rt = 0; rt < 2; ++rt) {
#pragma unroll
        for (int r = 0; r < 4; ++r) {
          int grow = row0 + m_base + rt * 16 + quad * 4 + r;
          if (grow >= N) continue;
          float o = acc[rt][jt][r] + bias;
          if (ct < 2)      qb[(size_t)grow * 128 + gcol]         = f2bf(o);
          else if (ct < 4) kb[(size_t)grow * 128 + (gcol - 128)] = f2bf(o);
          else if (ct < 6) vb[(size_t)grow * 128 + (gcol - 256)] = f2bf(o);
          else             outskip[(size_t)grow * 64 + (gcol - 384)] = o;
        }
      }
    }
    __syncthreads();  // all b-frag reads done before next ct restages Bs
  }
}

// ---- K5: attention ---------------------------------------------------------
// wave = 4 nodes (16 lanes each); within a node, 8 lanes per head; lane owns
// dims 8*l8..8*l8+7 (uint4 = 8 bf16). No max-tracking (|score| <~ 6).
#define EXPC 0.1803368801111244f  // log2(e)/8
__global__ __launch_bounds__(256) void attn_kernel(
    const ushort16* __restrict__ qb, const ushort16* __restrict__ kb,
    const ushort16* __restrict__ vb, const int* __restrict__ offs,
    const int* __restrict__ ssrc, float* __restrict__ out, int N) {
  int tid = threadIdx.x;
  int wave = tid >> 6, lane = tid & 63;
  int nsub = lane >> 4;
  int l16 = lane & 15;
  int head = l16 >> 3;
  int l8 = lane & 7;
  int node = (blockIdx.x * 4 + wave) * 4 + nsub;
  bool valid = node < N;
  int nodeC = valid ? node : 0;

  int e0 = 0, e1 = 0;
  if (valid) { e0 = offs[node]; e1 = offs[node + 1]; }
  int deg = e1 - e0;
  int md = deg;  // max degree across the wave's 4 nodes
  md = max(md, __shfl_xor(md, 16));
  md = max(md, __shfl_xor(md, 32));

  int hoff = head * 64 + l8 * 8;
  float qf[8];
  {
    uint4 qu = *(const uint4*)(qb + (size_t)nodeC * 128 + hoff);
    unpack8(qu, qf);
  }

  float l = 0.f;
  float a[8];
#pragma unroll
  for (int j = 0; j < 8; ++j) a[j] = 0.f;

  uint4 k0v = make_uint4(0, 0, 0, 0), v0v = k0v, k1v = k0v, v1v = k0v;
  if (md > 0) {
    int e = e0;
    int s = (e < e1) ? ssrc[e] : 0;
    k0v = *(const uint4*)(kb + (size_t)s * 128 + hoff);
    v0v = *(const uint4*)(vb + (size_t)s * 128 + hoff);
  }
  if (md > 1) {
    int e = e0 + 1;
    int s = (e < e1) ? ssrc[e] : 0;
    k1v = *(const uint4*)(kb + (size_t)s * 128 + hoff);
    v1v = *(const uint4*)(vb + (size_t)s * 128 + hoff);
  }

  for (int i = 0; i < md; ++i) {
    uint4 kc = k0v, vc = v0v;
    k0v = k1v; v0v = v1v;
    if (i + 2 < md) {
      int e = e0 + i + 2;
      int s = (e < e1) ? ssrc[e] : 0;
      k1v = *(const uint4*)(kb + (size_t)s * 128 + hoff);
      v1v = *(const uint4*)(vb + (size_t)s * 128 + hoff);
    }
    float kf[8], vf[8];
    unpack8(kc, kf);
    unpack8(vc, vf);
    float p = qf[0] * kf[0];
#pragma unroll
    for (int j = 1; j < 8; ++j) p = fmaf(qf[j], kf[j], p);
    p += __shfl_xor(p, 1);
    p += __shfl_xor(p, 2);
    p += __shfl_xor(p, 4);
    float w = (i < deg) ? exp2f(p * EXPC) : 0.f;
    l += w;
#pragma unroll
    for (int j = 0; j < 8; ++j) a[j] = fmaf(w, vf[j], a[j]);
  }

  float inv = (l > 0.f) ? 0.5f / l : 0.f;
  float r[8];
#pragma unroll
  for (int j = 0; j < 8; ++j) r[j] = a[j] * inv;
  // combine the two heads: lanes l16 and l16^8 hold the same out dims
#pragma unroll
  for (int j = 0; j < 8; ++j) r[j] += __shfl_xor(r[j], 8);

  if (valid && head == 0) {
    float* op = out + (size_t)node * 64 + l8 * 8;
    float4 c0 = *(float4*)op;
    float4 c1 = *(float4*)(op + 4);
    c0.x += r[0]; c0.y += r[1]; c0.z += r[2]; c0.w += r[3];
    c1.x += r[4]; c1.y += r[5]; c1.z += r[6]; c1.w += r[7];
    *(float4*)op = c0;
    *(float4*)(op + 4) = c1;
  }
}

extern "C" void kernel_launch(void* const* d_in, const int* in_sizes, int n_in,
                              void* d_out, int out_size, void* d_ws, size_t ws_size,
                              hipStream_t stream) {
  const int* n_id = (const int*)d_in[0];
  const int* eidx = (const int*)d_in[1];
  const float* memtab = (const float*)d_in[2];
  const float* embtab = (const float*)d_in[3];
  const float* Wq = (const float*)d_in[4];
  const float* bq = (const float*)d_in[5];
  const float* Wk = (const float*)d_in[6];
  const float* bk = (const float*)d_in[7];
  const float* Wv = (const float*)d_in[8];
  const float* bv = (const float*)d_in[9];
  const float* Wskip = (const float*)d_in[10];
  const float* bskip = (const float*)d_in[11];

  int N = in_sizes[0];
  int E = in_sizes[1] / 2;
  const int* srcA = eidx;
  const int* dstA = eidx + E;
  float* out = (float*)d_out;

  char* w = (char*)d_ws;
  ushort16* qb = (ushort16*)w; w += (size_t)N * 128 * 2;
  ushort16* kb = (ushort16*)w; w += (size_t)N * 128 * 2;
  ushort16* vb = (ushort16*)w; w += (size_t)N * 128 * 2;
  ushort16* Wt = (ushort16*)w; w += (size_t)448 * 128 * 2;
  float* ball = (float*)w;     w += (size_t)448 * 4;
  int* counts = (int*)w;       w += (size_t)N * 4;
  int* cursor = (int*)w;       w += (size_t)N * 4;
  int* offs = (int*)w;         w += (size_t)(N + 1) * 4;
  int* ssrc = (int*)w;         w += (size_t)E * 4;

  hipMemsetAsync(counts, 0, (size_t)2 * N * 4, stream);  // counts + cursor

  int k1_threads = (448 * 128 > E) ? 448 * 128 : E;
  prep_hist_kernel<<<(k1_threads + 255) / 256, 256, 0, stream>>>(
      Wq, bq, Wk, bk, Wv, bv, Wskip, bskip, Wt, ball, dstA, E, counts);

  scan_kernel<<<1, 1024, 0, stream>>>(counts, offs, N, E);

  scatter_kernel<<<(E + 255) / 256, 256, 0, stream>>>(srcA, dstA, E, offs, cursor, ssrc);

  qkv_mfma_kernel<<<(N + 127) / 128, 256, 0, stream>>>(
      n_id, embtab, memtab, Wt, ball, qb, kb, vb, out, N);

  attn_kernel<<<(N + 15) / 16, 256, 0, stream>>>(qb, kb, vb, offs, ssrc, out, N);
}

// Round 6
// 309.203 us; speedup vs baseline: 1.0978x; 1.0978x over previous
//
#include <hip/hip_runtime.h>
#include <math.h>

// ---------------------------------------------------------------------------
// TGN TransformerConv forward — 7 dispatches:
//   memset(counts|cursor)
//   K1 prep_hist: Wt bf16[448][128] (fused W^T) + ball f32[448] + dst histogram
//   K2 scan1 + K3 scan3: two-level prefix scan counts -> offs (CSR)
//   K4 scatter:   sorted_src by dst
//   K5 qkv_mfma:  2D grid (rowtile, 7 coltiles); gather(emb,mem)[n_id] fused
//                 into A-staging; SWAPPED-operand MFMA so the accumulator is
//                 row=lane&15 / cols=quad*4+reg -> coalesced uint2/float4
//                 epilogue stores (R5's 2B scalar stores were the GEMM cost).
//   K6 attn:      4 nodes/wave, 8 lanes/head (8 dims each, uint4 loads),
//                 no-max softmax (|score|<~6), 2-deep prefetch.
// R5 post-mortem: single-block scan + 1D-grid GEMM regressed; reverted.
// ---------------------------------------------------------------------------

typedef unsigned int uint32;
typedef unsigned short ushort16;
typedef __attribute__((ext_vector_type(8))) short short8;
typedef __attribute__((ext_vector_type(4))) float floatx4;

__device__ __forceinline__ ushort16 f2bf(float f) {
  union { float f; uint32 u; } x; x.f = f;
  uint32 r = x.u + 0x7fffu + ((x.u >> 16) & 1u);   // RNE
  return (ushort16)(r >> 16);
}
__device__ __forceinline__ float bf_lo(uint32 u) {
  union { uint32 u; float f; } x; x.u = u << 16; return x.f;
}
__device__ __forceinline__ float bf_hi(uint32 u) {
  union { uint32 u; float f; } x; x.u = u & 0xffff0000u; return x.f;
}
__device__ __forceinline__ void unpack8(uint4 u, float* f) {
  f[0] = bf_lo(u.x); f[1] = bf_hi(u.x); f[2] = bf_lo(u.y); f[3] = bf_hi(u.y);
  f[4] = bf_lo(u.z); f[5] = bf_hi(u.z); f[6] = bf_lo(u.w); f[7] = bf_hi(u.w);
}
__device__ __forceinline__ uint4 pack8(float4 a, float4 b) {
  uint4 r;
  r.x = (uint32)f2bf(a.x) | ((uint32)f2bf(a.y) << 16);
  r.y = (uint32)f2bf(a.z) | ((uint32)f2bf(a.w) << 16);
  r.z = (uint32)f2bf(b.x) | ((uint32)f2bf(b.y) << 16);
  r.w = (uint32)f2bf(b.z) | ((uint32)f2bf(b.w) << 16);
  return r;
}

// ---- K1: fuse+transpose weights to bf16 [448][128] + biases + histogram ----
__global__ __launch_bounds__(256) void prep_hist_kernel(
    const float* __restrict__ Wq, const float* __restrict__ bq,
    const float* __restrict__ Wk, const float* __restrict__ bk,
    const float* __restrict__ Wv, const float* __restrict__ bv,
    const float* __restrict__ Ws, const float* __restrict__ bs,
    ushort16* __restrict__ Wt, float* __restrict__ ball,
    const int* __restrict__ dstA, int E, int* __restrict__ counts) {
  int idx = blockIdx.x * 256 + threadIdx.x;
  if (idx < 448 * 128) {
    int n = idx >> 7, k = idx & 127;
    float w;
    if (n < 128)      w = Wq[k * 128 + n];
    else if (n < 256) w = Wk[k * 128 + (n - 128)];
    else if (n < 384) w = Wv[k * 128 + (n - 256)];
    else              w = Ws[k * 64 + (n - 384)];
    Wt[idx] = f2bf(w);
  }
  if (idx < 448) {
    float b;
    if (idx < 128)      b = bq[idx];
    else if (idx < 256) b = bk[idx - 128];
    else if (idx < 384) b = bv[idx - 256];
    else                b = bs[idx - 384];
    ball[idx] = b;
  }
  if (idx < E) atomicAdd(&counts[dstA[idx]], 1);
}

// ---- K2: per-block scan (4096 elems/block) --------------------------------
__global__ __launch_bounds__(256) void scan1_kernel(const int* __restrict__ counts,
                                                    int* __restrict__ offs,
                                                    int* __restrict__ bsum, int N) {
  __shared__ int s[256];
  int b = blockIdx.x, t = threadIdx.x;
  int base = b * 4096 + t * 16;
  int vals[16];
  int sum = 0;
#pragma unroll
  for (int i = 0; i < 16; ++i) {
    int idx = base + i;
    vals[i] = (idx < N) ? counts[idx] : 0;
    sum += vals[i];
  }
  s[t] = sum;
  __syncthreads();
  for (int off = 1; off < 256; off <<= 1) {
    int vv = (t >= off) ? s[t - off] : 0;
    __syncthreads();
    s[t] += vv;
    __syncthreads();
  }
  int run = (t > 0) ? s[t - 1] : 0;
#pragma unroll
  for (int i = 0; i < 16; ++i) {
    int idx = base + i;
    if (idx < N) offs[idx] = run;
    run += vals[i];
  }
  if (t == 255) bsum[b] = s[255];
}

// ---- K3: add cross-block prefix (bsum raw per-block sums; NB<=16) ----------
__global__ __launch_bounds__(256) void scan3_kernel(int* __restrict__ offs,
                                                    const int* __restrict__ bsum,
                                                    int N, int E) {
  int i = blockIdx.x * blockDim.x + threadIdx.x;
  if (i < N) {
    int blk = i >> 12;
    int add = 0;
    for (int j = 0; j < blk; ++j) add += bsum[j];
    offs[i] += add;
  }
  if (i == 0) offs[N] = E;
}

// ---- K4: scatter to CSR ----------------------------------------------------
__global__ __launch_bounds__(256) void scatter_kernel(
    const int* __restrict__ srcA, const int* __restrict__ dstA, int E,
    const int* __restrict__ offs, int* __restrict__ cursor,
    int* __restrict__ sorted_src) {
  int e = blockIdx.x * blockDim.x + threadIdx.x;
  if (e < E) {
    int d = dstA[e];
    int p = offs[d] + atomicAdd(&cursor[d], 1);
    sorted_src[p] = srcA[e];
  }
}

// ---- K5: gather-fused bf16 MFMA GEMM: concat(emb,mem)[n_id] @ [128,448] ----
// grid (ceil(N/128), 7). Swapped-operand MFMA: acc holds row m=lane&15,
// cols n=quad*4+reg -> each thread stores 4 consecutive cols of one row.
#define LDA 136  // 128 + 8 pad (bf16): ds_read_b128 frags land 2-way = free
__global__ __launch_bounds__(256) void qkv_mfma_kernel(
    const int* __restrict__ n_id, const float* __restrict__ embtab,
    const float* __restrict__ memtab,
    const ushort16* __restrict__ Wt, const float* __restrict__ ball,
    ushort16* __restrict__ qb, ushort16* __restrict__ kb, ushort16* __restrict__ vb,
    float* __restrict__ outskip, int N) {
  __shared__ ushort16 As[128 * LDA];
  __shared__ ushort16 Bs[64 * LDA];
  int t = threadIdx.x;
  int row0 = blockIdx.x * 128;
  int ct = blockIdx.y;
  int col0 = ct * 64;

  // stage A with gather+convert: 128 rows x 16 chunks of 8 f32 -> 8 bf16 (16B)
#pragma unroll
  for (int rep = 0; rep < 8; ++rep) {
    int idx = rep * 256 + t;
    int r = idx >> 4, c = idx & 15;
    int grow = row0 + r;
    uint4 outv = make_uint4(0u, 0u, 0u, 0u);
    if (grow < N) {
      int srcrow = n_id[grow];
      const float* srcp = (c < 8) ? (embtab + (size_t)srcrow * 64 + c * 8)
                                  : (memtab + (size_t)srcrow * 64 + (c - 8) * 8);
      float4 f0 = *(const float4*)srcp;
      float4 f1 = *(const float4*)(srcp + 4);
      outv = pack8(f0, f1);
    }
    *(uint4*)&As[r * LDA + c * 8] = outv;
  }
  // stage B tile 64x128
#pragma unroll
  for (int rep = 0; rep < 4; ++rep) {
    int idx = rep * 256 + t;
    int r = idx >> 4, c = idx & 15;
    uint4 val = *(const uint4*)(Wt + (size_t)(col0 + r) * 128 + c * 8);
    *(uint4*)&Bs[r * LDA + c * 8] = val;
  }
  __syncthreads();

  int wave = t >> 6, lane = t & 63;
  int m_base = wave * 32;
  int lrow = lane & 15, quad = lane >> 4;

  floatx4 acc[2][4];
#pragma unroll
  for (int i = 0; i < 2; ++i)
#pragma unroll
    for (int j = 0; j < 4; ++j) acc[i][j] = (floatx4)(0.f);

#pragma unroll
  for (int kk = 0; kk < 4; ++kk) {
    int koff = kk * 32 + quad * 8;
    short8 a0 = *(const short8*)&As[(m_base + lrow) * LDA + koff];
    short8 a1 = *(const short8*)&As[(m_base + 16 + lrow) * LDA + koff];
    short8 b0 = *(const short8*)&Bs[(lrow) * LDA + koff];
    short8 b1 = *(const short8*)&Bs[(16 + lrow) * LDA + koff];
    short8 b2 = *(const short8*)&Bs[(32 + lrow) * LDA + koff];
    short8 b3 = *(const short8*)&Bs[(48 + lrow) * LDA + koff];
    // SWAPPED operands: D = (X @ W^T)^T -> lane holds row=lrow, 4 cols
    acc[0][0] = __builtin_amdgcn_mfma_f32_16x16x32_bf16(b0, a0, acc[0][0], 0, 0, 0);
    acc[0][1] = __builtin_amdgcn_mfma_f32_16x16x32_bf16(b1, a0, acc[0][1], 0, 0, 0);
    acc[0][2] = __builtin_amdgcn_mfma_f32_16x16x32_bf16(b2, a0, acc[0][2], 0, 0, 0);
    acc[0][3] = __builtin_amdgcn_mfma_f32_16x16x32_bf16(b3, a0, acc[0][3], 0, 0, 0);
    acc[1][0] = __builtin_amdgcn_mfma_f32_16x16x32_bf16(b0, a1, acc[1][0], 0, 0, 0);
    acc[1][1] = __builtin_amdgcn_mfma_f32_16x16x32_bf16(b1, a1, acc[1][1], 0, 0, 0);
    acc[1][2] = __builtin_amdgcn_mfma_f32_16x16x32_bf16(b2, a1, acc[1][2], 0, 0, 0);
    acc[1][3] = __builtin_amdgcn_mfma_f32_16x16x32_bf16(b3, a1, acc[1][3], 0, 0, 0);
  }

  // epilogue: lane holds row grow, cols gcol..gcol+3 (consecutive)
#pragma unroll
  for (int jt = 0; jt < 4; ++jt) {
    int gcol = col0 + jt * 16 + quad * 4;
    float4 bias = *(const float4*)(ball + gcol);
#pragma unroll
    for (int rt = 0; rt < 2; ++rt) {
      int grow = row0 + m_base + rt * 16 + lrow;
      if (grow >= N) continue;
      float o0 = acc[rt][jt][0] + bias.x;
      float o1 = acc[rt][jt][1] + bias.y;
      float o2 = acc[rt][jt][2] + bias.z;
      float o3 = acc[rt][jt][3] + bias.w;
      if (ct < 6) {
        uint2 pk;
        pk.x = (uint32)f2bf(o0) | ((uint32)f2bf(o1) << 16);
        pk.y = (uint32)f2bf(o2) | ((uint32)f2bf(o3) << 16);
        if (ct < 2)      *(uint2*)(qb + (size_t)grow * 128 + gcol)         = pk;
        else if (ct < 4) *(uint2*)(kb + (size_t)grow * 128 + (gcol - 128)) = pk;
        else             *(uint2*)(vb + (size_t)grow * 128 + (gcol - 256)) = pk;
      } else {
        *(float4*)(outskip + (size_t)grow * 64 + (gcol - 384)) =
            make_float4(o0, o1, o2, o3);
      }
    }
  }
}

// ---- K6: attention ---------------------------------------------------------
// wave = 4 nodes (16 lanes each); within a node, 8 lanes per head; lane owns
// dims 8*l8..8*l8+7 (uint4 = 8 bf16). No max-tracking (|score| <~ 6).
#define EXPC 0.1803368801111244f  // log2(e)/8
__global__ __launch_bounds__(256) void attn_kernel(
    const ushort16* __restrict__ qb, const ushort16* __restrict__ kb,
    const ushort16* __restrict__ vb, const int* __restrict__ offs,
    const int* __restrict__ ssrc, float* __restrict__ out, int N) {
  int tid = threadIdx.x;
  int wave = tid >> 6, lane = tid & 63;
  int nsub = lane >> 4;
  int l16 = lane & 15;
  int head = l16 >> 3;
  int l8 = lane & 7;
  int node = (blockIdx.x * 4 + wave) * 4 + nsub;
  bool valid = node < N;
  int nodeC = valid ? node : 0;

  int e0 = 0, e1 = 0;
  if (valid) { e0 = offs[node]; e1 = offs[node + 1]; }
  int deg = e1 - e0;
  int md = deg;  // max degree across the wave's 4 nodes
  md = max(md, __shfl_xor(md, 16));
  md = max(md, __shfl_xor(md, 32));

  int hoff = head * 64 + l8 * 8;
  float qf[8];
  {
    uint4 qu = *(const uint4*)(qb + (size_t)nodeC * 128 + hoff);
    unpack8(qu, qf);
  }

  float l = 0.f;
  float a[8];
#pragma unroll
  for (int j = 0; j < 8; ++j) a[j] = 0.f;

  uint4 k0v = make_uint4(0, 0, 0, 0), v0v = k0v, k1v = k0v, v1v = k0v;
  if (md > 0) {
    int e = e0;
    int s = (e < e1) ? ssrc[e] : 0;
    k0v = *(const uint4*)(kb + (size_t)s * 128 + hoff);
    v0v = *(const uint4*)(vb + (size_t)s * 128 + hoff);
  }
  if (md > 1) {
    int e = e0 + 1;
    int s = (e < e1) ? ssrc[e] : 0;
    k1v = *(const uint4*)(kb + (size_t)s * 128 + hoff);
    v1v = *(const uint4*)(vb + (size_t)s * 128 + hoff);
  }

  for (int i = 0; i < md; ++i) {
    uint4 kc = k0v, vc = v0v;
    k0v = k1v; v0v = v1v;
    if (i + 2 < md) {
      int e = e0 + i + 2;
      int s = (e < e1) ? ssrc[e] : 0;
      k1v = *(const uint4*)(kb + (size_t)s * 128 + hoff);
      v1v = *(const uint4*)(vb + (size_t)s * 128 + hoff);
    }
    float kf[8], vf[8];
    unpack8(kc, kf);
    unpack8(vc, vf);
    float p = qf[0] * kf[0];
#pragma unroll
    for (int j = 1; j < 8; ++j) p = fmaf(qf[j], kf[j], p);
    p += __shfl_xor(p, 1);
    p += __shfl_xor(p, 2);
    p += __shfl_xor(p, 4);
    float w = (i < deg) ? exp2f(p * EXPC) : 0.f;
    l += w;
#pragma unroll
    for (int j = 0; j < 8; ++j) a[j] = fmaf(w, vf[j], a[j]);
  }

  float inv = (l > 0.f) ? 0.5f / l : 0.f;
  float r[8];
#pragma unroll
  for (int j = 0; j < 8; ++j) r[j] = a[j] * inv;
  // combine the two heads: lanes l16 and l16^8 hold the same out dims
#pragma unroll
  for (int j = 0; j < 8; ++j) r[j] += __shfl_xor(r[j], 8);

  if (valid && head == 0) {
    float* op = out + (size_t)node * 64 + l8 * 8;
    float4 c0 = *(float4*)op;
    float4 c1 = *(float4*)(op + 4);
    c0.x += r[0]; c0.y += r[1]; c0.z += r[2]; c0.w += r[3];
    c1.x += r[4]; c1.y += r[5]; c1.z += r[6]; c1.w += r[7];
    *(float4*)op = c0;
    *(float4*)(op + 4) = c1;
  }
}

extern "C" void kernel_launch(void* const* d_in, const int* in_sizes, int n_in,
                              void* d_out, int out_size, void* d_ws, size_t ws_size,
                              hipStream_t stream) {
  const int* n_id = (const int*)d_in[0];
  const int* eidx = (const int*)d_in[1];
  const float* memtab = (const float*)d_in[2];
  const float* embtab = (const float*)d_in[3];
  const float* Wq = (const float*)d_in[4];
  const float* bq = (const float*)d_in[5];
  const float* Wk = (const float*)d_in[6];
  const float* bk = (const float*)d_in[7];
  const float* Wv = (const float*)d_in[8];
  const float* bv = (const float*)d_in[9];
  const float* Wskip = (const float*)d_in[10];
  const float* bskip = (const float*)d_in[11];

  int N = in_sizes[0];
  int E = in_sizes[1] / 2;
  const int* srcA = eidx;
  const int* dstA = eidx + E;
  float* out = (float*)d_out;

  char* w = (char*)d_ws;
  ushort16* qb = (ushort16*)w; w += (size_t)N * 128 * 2;
  ushort16* kb = (ushort16*)w; w += (size_t)N * 128 * 2;
  ushort16* vb = (ushort16*)w; w += (size_t)N * 128 * 2;
  ushort16* Wt = (ushort16*)w; w += (size_t)448 * 128 * 2;
  float* ball = (float*)w;     w += (size_t)448 * 4;
  int* counts = (int*)w;       w += (size_t)N * 4;
  int* cursor = (int*)w;       w += (size_t)N * 4;
  int* offs = (int*)w;         w += (size_t)(N + 1) * 4;
  int* bsum = (int*)w;         w += (size_t)1024 * 4;
  int* ssrc = (int*)w;         w += (size_t)E * 4;

  hipMemsetAsync(counts, 0, (size_t)2 * N * 4, stream);  // counts + cursor

  int k1_threads = (448 * 128 > E) ? 448 * 128 : E;
  prep_hist_kernel<<<(k1_threads + 255) / 256, 256, 0, stream>>>(
      Wq, bq, Wk, bk, Wv, bv, Wskip, bskip, Wt, ball, dstA, E, counts);

  int NB = (N + 4095) / 4096;
  scan1_kernel<<<NB, 256, 0, stream>>>(counts, offs, bsum, N);
  scan3_kernel<<<(N + 255) / 256, 256, 0, stream>>>(offs, bsum, N, E);

  scatter_kernel<<<(E + 255) / 256, 256, 0, stream>>>(srcA, dstA, E, offs, cursor, ssrc);

  dim3 ggrid((N + 127) / 128, 7);
  qkv_mfma_kernel<<<ggrid, 256, 0, stream>>>(
      n_id, embtab, memtab, Wt, ball, qb, kb, vb, out, N);

  attn_kernel<<<(N + 15) / 16, 256, 0, stream>>>(qb, kb, vb, offs, ssrc, out, N);
}